// Round 6
// baseline (377.900 us; speedup 1.0000x reference)
//
#include <hip/hip_runtime.h>
#include <math.h>

// TopKMoEGate via split-bf16 MFMA:
//   x = xh + xl, W = wh + wl (bf16 hi/lo); logits = xh*wh + xh*wl + xl*wh
//   (fp32-accurate to ~5e-6; wave-parallel fp64 tie-guard on top-3 candidates).
// R6: W pre-converted to bf16 hi/lo planes in d_ws by a pre-kernel (kills 2/3
//     of in-loop split2 VALU); global->reg prefetch distance 2 (covers loaded
//     HBM latency ~900-2000 cyc with a full chunk-iteration of slack).
// Block: 32 tokens x 64 experts, BK=64, double-buffered LDS, 1 barrier/iter.

typedef __attribute__((ext_vector_type(8))) __bf16 bf16x8;
typedef __attribute__((ext_vector_type(8))) unsigned short u16x8;
typedef __attribute__((ext_vector_type(4))) float f32x4;

constexpr int EXPN = 64;   // experts
constexpr int BM   = 32;   // tokens per block
constexpr int BK   = 64;   // k chunk
constexpr int LDK  = BK + 8;  // 72 bf16 = 144 B row stride (16B-aligned)

__device__ __forceinline__ void split2(float f, unsigned short& h, unsigned short& l) {
    const unsigned b = __float_as_uint(f);
    h = (unsigned short)(b >> 16);                       // bf16 hi (truncate)
    const float fh = __uint_as_float(b & 0xffff0000u);
    l = (unsigned short)(__float_as_uint(f - fh) >> 16); // bf16 lo
}

// ---- pre-kernel: W fp32 -> wh/wl bf16 planes (same split2 numerics) ----
__global__ __launch_bounds__(256)
void convert_w_kernel(const float* __restrict__ W,
                      unsigned short* __restrict__ whp,
                      unsigned short* __restrict__ wlp, int n4)
{
    const int i = blockIdx.x * 256 + threadIdx.x;   // float4 index
    if (i >= n4) return;
    const float4 v = *(const float4*)(W + (size_t)i * 4);
    const float f[4] = {v.x, v.y, v.z, v.w};
    unsigned short h[4], l[4];
#pragma unroll
    for (int j = 0; j < 4; ++j) split2(f[j], h[j], l[j]);
    *(ushort4*)(whp + (size_t)i * 4) = make_ushort4(h[0], h[1], h[2], h[3]);
    *(ushort4*)(wlp + (size_t)i * 4) = make_ushort4(l[0], l[1], l[2], l[3]);
}

__global__ __launch_bounds__(256)
void moe_gate_kernel(const float* __restrict__ x,      // [M, D]
                     const float* __restrict__ W,      // [E, D] (fp64 guard only)
                     const unsigned short* __restrict__ whp,  // [E, D] bf16 hi
                     const unsigned short* __restrict__ wlp,  // [E, D] bf16 lo
                     const float* __restrict__ nw,     // [E]
                     const float* __restrict__ noise,  // [M, E]
                     float* __restrict__ probs,        // [M, E]
                     float* __restrict__ idx_out,      // [M, 2] float-encoded
                     float* __restrict__ val_out,      // [M, 2]
                     int D)
{
    __shared__ unsigned short xh[2][BM][LDK], xl[2][BM][LDK];     // 18.4 KB
    __shared__ unsigned short wh[2][EXPN][LDK], wl[2][EXPN][LDK]; // 36.9 KB
    __shared__ float ls[BM][EXPN + 1];                            // 8.3 KB

    const int tid  = threadIdx.x;
    const int lane = tid & 63;
    const int wv   = tid >> 6;
    const int hh   = wv & 1;        // token half (16 tokens)
    const int qq   = wv >> 1;       // expert half (32 experts)
    const int m0   = blockIdx.x * BM;

    // staging assignment
    const int xrow = tid >> 3;          // 0..31 token
    const int xcol = (tid & 7) * 8;     // k offset (8 floats / thread)
    const int wrow = tid >> 2;          // 0..63 expert
    const int wcol = (tid & 3) * 16;    // k offset (16 bf16 / thread)

    const float*          xbase  = x   + (size_t)(m0 + xrow) * D + xcol;
    const unsigned short* whbase = whp + (size_t)wrow * D + wcol;
    const unsigned short* wlbase = wlp + (size_t)wrow * D + wcol;

    f32x4 acc0 = {0.f, 0.f, 0.f, 0.f};
    f32x4 acc1 = {0.f, 0.f, 0.f, 0.f};

    // prefetch slots (distance 2)
    float4 px0[2], px1[2];
    u16x8  pwh0[2], pwh1[2], pwl0[2], pwl1[2];

    px0[0]  = *(const float4*)(xbase);
    px1[0]  = *(const float4*)(xbase + 4);
    pwh0[0] = *(const u16x8*)(whbase);
    pwh1[0] = *(const u16x8*)(whbase + 8);
    pwl0[0] = *(const u16x8*)(wlbase);
    pwl1[0] = *(const u16x8*)(wlbase + 8);

    px0[1]  = *(const float4*)(xbase + BK);
    px1[1]  = *(const float4*)(xbase + BK + 4);
    pwh0[1] = *(const u16x8*)(whbase + BK);
    pwh1[1] = *(const u16x8*)(whbase + BK + 8);
    pwl0[1] = *(const u16x8*)(wlbase + BK);
    pwl1[1] = *(const u16x8*)(wlbase + BK + 8);

    const int nchunk = D / BK;          // 32
    const int fr = lane & 15;           // m (tokens) / n (experts) in frag
    const int kq = (lane >> 4) * 8;     // k sub-offset in frag

    for (int c = 0; c < nchunk; ++c) {
        const int buf = c & 1;

        // ---- stage into LDS (x: convert; W: straight copy) ----
        {
            const float xv[8] = {px0[buf].x, px0[buf].y, px0[buf].z, px0[buf].w,
                                 px1[buf].x, px1[buf].y, px1[buf].z, px1[buf].w};
            u16x8 hv, lv;
#pragma unroll
            for (int i = 0; i < 8; ++i) {
                unsigned short a, b; split2(xv[i], a, b);
                hv[i] = a; lv[i] = b;
            }
            *(u16x8*)&xh[buf][xrow][xcol] = hv;
            *(u16x8*)&xl[buf][xrow][xcol] = lv;

            *(u16x8*)&wh[buf][wrow][wcol]     = pwh0[buf];
            *(u16x8*)&wh[buf][wrow][wcol + 8] = pwh1[buf];
            *(u16x8*)&wl[buf][wrow][wcol]     = pwl0[buf];
            *(u16x8*)&wl[buf][wrow][wcol + 8] = pwl1[buf];
        }
        __syncthreads();

        // ---- prefetch chunk c+2 into the slot just consumed ----
        if (c + 2 < nchunk) {
            const int ko = (c + 2) * BK;
            px0[buf]  = *(const float4*)(xbase + ko);
            px1[buf]  = *(const float4*)(xbase + ko + 4);
            pwh0[buf] = *(const u16x8*)(whbase + ko);
            pwh1[buf] = *(const u16x8*)(whbase + ko + 8);
            pwl0[buf] = *(const u16x8*)(wlbase + ko);
            pwl1[buf] = *(const u16x8*)(wlbase + ko + 8);
        }

        // ---- MFMA on current chunk ----
#pragma unroll
        for (int ks = 0; ks < BK; ks += 32) {
            const bf16x8 ah  = *(const bf16x8*)&xh[buf][hh * 16 + fr][ks + kq];
            const bf16x8 al  = *(const bf16x8*)&xl[buf][hh * 16 + fr][ks + kq];
            const bf16x8 b0h = *(const bf16x8*)&wh[buf][qq * 32 + fr][ks + kq];
            const bf16x8 b0l = *(const bf16x8*)&wl[buf][qq * 32 + fr][ks + kq];
            const bf16x8 b1h = *(const bf16x8*)&wh[buf][qq * 32 + 16 + fr][ks + kq];
            const bf16x8 b1l = *(const bf16x8*)&wl[buf][qq * 32 + 16 + fr][ks + kq];
            acc0 = __builtin_amdgcn_mfma_f32_16x16x32_bf16(ah, b0h, acc0, 0, 0, 0);
            acc0 = __builtin_amdgcn_mfma_f32_16x16x32_bf16(ah, b0l, acc0, 0, 0, 0);
            acc0 = __builtin_amdgcn_mfma_f32_16x16x32_bf16(al, b0h, acc0, 0, 0, 0);
            acc1 = __builtin_amdgcn_mfma_f32_16x16x32_bf16(ah, b1h, acc1, 0, 0, 0);
            acc1 = __builtin_amdgcn_mfma_f32_16x16x32_bf16(ah, b1l, acc1, 0, 0, 0);
            acc1 = __builtin_amdgcn_mfma_f32_16x16x32_bf16(al, b1h, acc1, 0, 0, 0);
        }
    }

    // ---- C/D layout: col = lane&15, row = (lane>>4)*4 + reg ----
    const int trow = hh * 16 + (lane >> 4) * 4;
#pragma unroll
    for (int r = 0; r < 4; ++r) {
        ls[trow + r][qq * 32 + fr]      = acc0[r];
        ls[trow + r][qq * 32 + 16 + fr] = acc1[r];
    }
    __syncthreads();

    // ---- epilogue: per-token noisy top-2 + sparse softmax (lane = expert) ----
    const float nwv = nw[lane];

#pragma unroll 1
    for (int t = 0; t < 8; ++t) {
        const int tl = wv * 8 + t;       // local token
        const int g  = m0 + tl;          // global token
        const float logit = fmaf(noise[(size_t)g * EXPN + lane], nwv, ls[tl][lane]);

        float v0; int i0;
        {
            float v = logit; int ix = lane;
#pragma unroll
            for (int off = 32; off; off >>= 1) {
                const float vo = __shfl_xor(v, off);
                const int   io = __shfl_xor(ix, off);
                if (vo > v || (vo == v && io < ix)) { v = vo; ix = io; }
            }
            v0 = v; i0 = ix;
        }
        float v1; int i1;
        {
            float v = (lane == i0) ? -INFINITY : logit; int ix = lane;
#pragma unroll
            for (int off = 32; off; off >>= 1) {
                const float vo = __shfl_xor(v, off);
                const int   io = __shfl_xor(ix, off);
                if (vo > v || (vo == v && io < ix)) { v = vo; ix = io; }
            }
            v1 = v; i1 = ix;
        }
        float v2; int i2;
        {
            float v = (lane == i0 || lane == i1) ? -INFINITY : logit; int ix = lane;
#pragma unroll
            for (int off = 32; off; off >>= 1) {
                const float vo = __shfl_xor(v, off);
                const int   io = __shfl_xor(ix, off);
                if (vo > v || (vo == v && io < ix)) { v = vo; ix = io; }
            }
            v2 = v; i2 = ix;
        }

        // near-tie guard: wave-parallel fp64 recompute of the 3 candidate
        // logits (lanes stride K by 64 -> coalesced; butterfly fp64 sum).
        const float eps = 1e-3f;
        if ((v0 - v1) < eps || (v1 - v2) < eps) {
            const float* xr  = x + (size_t)g * D;
            const float* w0r = W + (size_t)i0 * D;
            const float* w1r = W + (size_t)i1 * D;
            const float* w2r = W + (size_t)i2 * D;
            double s0 = 0.0, s1 = 0.0, s2 = 0.0;
            for (int d = lane; d < D; d += 64) {
                const double xv = (double)xr[d];
                s0 += xv * (double)w0r[d];
                s1 += xv * (double)w1r[d];
                s2 += xv * (double)w2r[d];
            }
#pragma unroll
            for (int off = 32; off; off >>= 1) {
                s0 += __shfl_xor(s0, off);
                s1 += __shfl_xor(s1, off);
                s2 += __shfl_xor(s2, off);
            }
            double d0 = s0 + (double)noise[(size_t)g * EXPN + i0] * (double)nw[i0];
            double d1 = s1 + (double)noise[(size_t)g * EXPN + i1] * (double)nw[i1];
            double d2 = s2 + (double)noise[(size_t)g * EXPN + i2] * (double)nw[i2];
            // sort 3 (value desc, index asc on ties)
            #define CSWAP(va, ia, vb, ib)                                   \
                if ((vb > va) || (vb == va && ib < ia)) {                   \
                    double tv = va; va = vb; vb = tv;                       \
                    int ti = ia; ia = ib; ib = ti; }
            CSWAP(d0, i0, d1, i1)
            CSWAP(d1, i1, d2, i2)
            CSWAP(d0, i0, d1, i1)
            #undef CSWAP
            v0 = (float)d0; v1 = (float)d1;
        }

        const float e1  = expf(v1 - v0);
        const float inv = 1.0f / (1.0f + e1);

        float p = 0.f;
        if (lane == i0)      p = inv;
        else if (lane == i1) p = e1 * inv;
        probs[(size_t)g * EXPN + lane] = p;

        if (lane == 0) {
            idx_out[(size_t)g * 2 + 0] = (float)i0;
            idx_out[(size_t)g * 2 + 1] = (float)i1;
            val_out[(size_t)g * 2 + 0] = v0;
            val_out[(size_t)g * 2 + 1] = v1;
        }
    }
}

extern "C" void kernel_launch(void* const* d_in, const int* in_sizes, int n_in,
                              void* d_out, int out_size, void* d_ws, size_t ws_size,
                              hipStream_t stream) {
    const float* x     = (const float*)d_in[0];  // [B,S,D]
    const float* W     = (const float*)d_in[1];  // [E,D]
    const float* nw    = (const float*)d_in[2];  // [E]
    const float* noise = (const float*)d_in[3];  // [B,S,E]

    const int M = in_sizes[3] / EXPN;            // 16384 tokens
    const int D = in_sizes[0] / M;               // 2048
    const int wn = in_sizes[1];                  // E*D = 131072

    unsigned short* whp = (unsigned short*)d_ws;            // [E,D] bf16 hi
    unsigned short* wlp = whp + (size_t)wn;                 // [E,D] bf16 lo

    float* probs   = (float*)d_out;              // [M, E]
    float* idx_out = probs + (size_t)M * EXPN;   // [M, 2]
    float* val_out = idx_out + (size_t)M * 2;    // [M, 2]

    const int n4 = wn / 4;
    convert_w_kernel<<<(n4 + 255) / 256, 256, 0, stream>>>(W, whp, wlp, n4);

    const int grid = M / BM;                     // 512 blocks
    moe_gate_kernel<<<grid, 256, 0, stream>>>(x, W, whp, wlp, nw, noise,
                                              probs, idx_out, val_out, D);
}

// Round 7
// 229.432 us; speedup vs baseline: 1.6471x; 1.6471x over previous
//
#include <hip/hip_runtime.h>
#include <math.h>

// TopKMoEGate via split-bf16 MFMA:
//   x = xh + xl, W = wh + wl (bf16 hi/lo); logits = xh*wh + xh*wl + xl*wh
//   (fp32-accurate to ~5e-6; wave-parallel fp64 tie-guard on top-3 candidates).
// R7: W pre-converted to bf16 planes (pre-kernel, kills 2/3 of in-loop split2
//     VALU). Distance-2 global->reg prefetch via EXPLICIT unroll-by-2 with two
//     named scalar register sets (R6's dynamic-indexed arrays got promoted to
//     LDS/scratch by the compiler -> 2.5x regression; never index registers).
// Block: 32 tokens x 64 experts, BK=64, double-buffered LDS, 1 barrier/chunk.

typedef __attribute__((ext_vector_type(8))) __bf16 bf16x8;
typedef __attribute__((ext_vector_type(8))) unsigned short u16x8;
typedef __attribute__((ext_vector_type(4))) float f32x4;

constexpr int EXPN = 64;   // experts
constexpr int BM   = 32;   // tokens per block
constexpr int BK   = 64;   // k chunk
constexpr int LDK  = BK + 8;  // 72 bf16 = 144 B row stride (16B-aligned)

__device__ __forceinline__ void split2(float f, unsigned short& h, unsigned short& l) {
    const unsigned b = __float_as_uint(f);
    h = (unsigned short)(b >> 16);                       // bf16 hi (truncate)
    const float fh = __uint_as_float(b & 0xffff0000u);
    l = (unsigned short)(__float_as_uint(f - fh) >> 16); // bf16 lo
}

// ---- pre-kernel: W fp32 -> wh/wl bf16 planes (same split2 numerics) ----
__global__ __launch_bounds__(256)
void convert_w_kernel(const float* __restrict__ W,
                      unsigned short* __restrict__ whp,
                      unsigned short* __restrict__ wlp, int n4)
{
    const int i = blockIdx.x * 256 + threadIdx.x;   // float4 index
    if (i >= n4) return;
    const float4 v = *(const float4*)(W + (size_t)i * 4);
    const float f[4] = {v.x, v.y, v.z, v.w};
    unsigned short h[4], l[4];
#pragma unroll
    for (int j = 0; j < 4; ++j) split2(f[j], h[j], l[j]);
    *(ushort4*)(whp + (size_t)i * 4) = make_ushort4(h[0], h[1], h[2], h[3]);
    *(ushort4*)(wlp + (size_t)i * 4) = make_ushort4(l[0], l[1], l[2], l[3]);
}

__global__ __launch_bounds__(256)
void moe_gate_kernel(const float* __restrict__ x,      // [M, D]
                     const float* __restrict__ W,      // [E, D] (fp64 guard only)
                     const unsigned short* __restrict__ whp,  // [E, D] bf16 hi
                     const unsigned short* __restrict__ wlp,  // [E, D] bf16 lo
                     const float* __restrict__ nw,     // [E]
                     const float* __restrict__ noise,  // [M, E]
                     float* __restrict__ probs,        // [M, E]
                     float* __restrict__ idx_out,      // [M, 2] float-encoded
                     float* __restrict__ val_out,      // [M, 2]
                     int D)
{
    __shared__ unsigned short xh[2][BM][LDK], xl[2][BM][LDK];     // 18.4 KB
    __shared__ unsigned short wh[2][EXPN][LDK], wl[2][EXPN][LDK]; // 36.9 KB
    __shared__ float ls[BM][EXPN + 1];                            // 8.3 KB

    const int tid  = threadIdx.x;
    const int lane = tid & 63;
    const int wv   = tid >> 6;
    const int hh   = wv & 1;        // token half (16 tokens)
    const int qq   = wv >> 1;       // expert half (32 experts)
    const int m0   = blockIdx.x * BM;

    // staging assignment
    const int xrow = tid >> 3;          // 0..31 token
    const int xcol = (tid & 7) * 8;     // k offset (8 floats / thread)
    const int wrow = tid >> 2;          // 0..63 expert
    const int wcol = (tid & 3) * 16;    // k offset (16 bf16 / thread)

    const float*          xbase  = x   + (size_t)(m0 + xrow) * D + xcol;
    const unsigned short* whbase = whp + (size_t)wrow * D + wcol;
    const unsigned short* wlbase = wlp + (size_t)wrow * D + wcol;

    f32x4 acc0 = {0.f, 0.f, 0.f, 0.f};
    f32x4 acc1 = {0.f, 0.f, 0.f, 0.f};

    const int nchunk = D / BK;          // 32 (even)
    const int fr = lane & 15;           // m (tokens) / n (experts) in frag
    const int kq = (lane >> 4) * 8;     // k sub-offset in frag

    // prefetch register sets: A = even chunk, B = odd chunk (named scalars!)
    float4 ax0, ax1, bx0, bx1;
    u16x8  awh0, awh1, awl0, awl1, bwh0, bwh1, bwl0, bwl1;

#define LOAD_SET(X0, X1, WH0, WH1, WL0, WL1, ko)                        \
    X0  = *(const float4*)(xbase  + (ko));                              \
    X1  = *(const float4*)(xbase  + (ko) + 4);                          \
    WH0 = *(const u16x8*)(whbase + (ko));                               \
    WH1 = *(const u16x8*)(whbase + (ko) + 8);                           \
    WL0 = *(const u16x8*)(wlbase + (ko));                               \
    WL1 = *(const u16x8*)(wlbase + (ko) + 8);

#define STAGE_SET(X0, X1, WH0, WH1, WL0, WL1, b)                        \
    {                                                                   \
        const float xv_[8] = {X0.x, X0.y, X0.z, X0.w,                   \
                              X1.x, X1.y, X1.z, X1.w};                  \
        u16x8 hv_, lv_;                                                 \
        _Pragma("unroll")                                               \
        for (int i_ = 0; i_ < 8; ++i_) {                                \
            unsigned short a_, b_; split2(xv_[i_], a_, b_);             \
            hv_[i_] = a_; lv_[i_] = b_;                                 \
        }                                                               \
        *(u16x8*)&xh[b][xrow][xcol] = hv_;                              \
        *(u16x8*)&xl[b][xrow][xcol] = lv_;                              \
        *(u16x8*)&wh[b][wrow][wcol]     = WH0;                          \
        *(u16x8*)&wh[b][wrow][wcol + 8] = WH1;                          \
        *(u16x8*)&wl[b][wrow][wcol]     = WL0;                          \
        *(u16x8*)&wl[b][wrow][wcol + 8] = WL1;                          \
    }

#define MFMA_CHUNK(b)                                                   \
    _Pragma("unroll")                                                   \
    for (int ks = 0; ks < BK; ks += 32) {                               \
        const bf16x8 ah  = *(const bf16x8*)&xh[b][hh * 16 + fr][ks + kq]; \
        const bf16x8 al  = *(const bf16x8*)&xl[b][hh * 16 + fr][ks + kq]; \
        const bf16x8 b0h = *(const bf16x8*)&wh[b][qq * 32 + fr][ks + kq]; \
        const bf16x8 b0l = *(const bf16x8*)&wl[b][qq * 32 + fr][ks + kq]; \
        const bf16x8 b1h = *(const bf16x8*)&wh[b][qq * 32 + 16 + fr][ks + kq]; \
        const bf16x8 b1l = *(const bf16x8*)&wl[b][qq * 32 + 16 + fr][ks + kq]; \
        acc0 = __builtin_amdgcn_mfma_f32_16x16x32_bf16(ah, b0h, acc0, 0, 0, 0); \
        acc0 = __builtin_amdgcn_mfma_f32_16x16x32_bf16(ah, b0l, acc0, 0, 0, 0); \
        acc0 = __builtin_amdgcn_mfma_f32_16x16x32_bf16(al, b0h, acc0, 0, 0, 0); \
        acc1 = __builtin_amdgcn_mfma_f32_16x16x32_bf16(ah, b1h, acc1, 0, 0, 0); \
        acc1 = __builtin_amdgcn_mfma_f32_16x16x32_bf16(ah, b1l, acc1, 0, 0, 0); \
        acc1 = __builtin_amdgcn_mfma_f32_16x16x32_bf16(al, b1h, acc1, 0, 0, 0); \
    }

    LOAD_SET(ax0, ax1, awh0, awh1, awl0, awl1, 0)
    LOAD_SET(bx0, bx1, bwh0, bwh1, bwl0, bwl1, BK)

    for (int c = 0; c < nchunk; c += 2) {
        // ---- even chunk: stage A -> buf0, prefetch c+2 into A ----
        STAGE_SET(ax0, ax1, awh0, awh1, awl0, awl1, 0)
        __syncthreads();
        if (c + 2 < nchunk) {
            LOAD_SET(ax0, ax1, awh0, awh1, awl0, awl1, (c + 2) * BK)
        }
        MFMA_CHUNK(0)

        // ---- odd chunk: stage B -> buf1, prefetch c+3 into B ----
        STAGE_SET(bx0, bx1, bwh0, bwh1, bwl0, bwl1, 1)
        __syncthreads();
        if (c + 3 < nchunk) {
            LOAD_SET(bx0, bx1, bwh0, bwh1, bwl0, bwl1, (c + 3) * BK)
        }
        MFMA_CHUNK(1)
    }

#undef LOAD_SET
#undef STAGE_SET
#undef MFMA_CHUNK

    // ---- C/D layout: col = lane&15, row = (lane>>4)*4 + reg ----
    const int trow = hh * 16 + (lane >> 4) * 4;
#pragma unroll
    for (int r = 0; r < 4; ++r) {
        ls[trow + r][qq * 32 + fr]      = acc0[r];
        ls[trow + r][qq * 32 + 16 + fr] = acc1[r];
    }
    __syncthreads();

    // ---- epilogue: per-token noisy top-2 + sparse softmax (lane = expert) ----
    const float nwv = nw[lane];

#pragma unroll 1
    for (int t = 0; t < 8; ++t) {
        const int tl = wv * 8 + t;       // local token
        const int g  = m0 + tl;          // global token
        const float logit = fmaf(noise[(size_t)g * EXPN + lane], nwv, ls[tl][lane]);

        float v0; int i0;
        {
            float v = logit; int ix = lane;
#pragma unroll
            for (int off = 32; off; off >>= 1) {
                const float vo = __shfl_xor(v, off);
                const int   io = __shfl_xor(ix, off);
                if (vo > v || (vo == v && io < ix)) { v = vo; ix = io; }
            }
            v0 = v; i0 = ix;
        }
        float v1; int i1;
        {
            float v = (lane == i0) ? -INFINITY : logit; int ix = lane;
#pragma unroll
            for (int off = 32; off; off >>= 1) {
                const float vo = __shfl_xor(v, off);
                const int   io = __shfl_xor(ix, off);
                if (vo > v || (vo == v && io < ix)) { v = vo; ix = io; }
            }
            v1 = v; i1 = ix;
        }
        float v2; int i2;
        {
            float v = (lane == i0 || lane == i1) ? -INFINITY : logit; int ix = lane;
#pragma unroll
            for (int off = 32; off; off >>= 1) {
                const float vo = __shfl_xor(v, off);
                const int   io = __shfl_xor(ix, off);
                if (vo > v || (vo == v && io < ix)) { v = vo; ix = io; }
            }
            v2 = v; i2 = ix;
        }

        // near-tie guard: wave-parallel fp64 recompute of the 3 candidate
        // logits (lanes stride K by 64 -> coalesced; butterfly fp64 sum).
        const float eps = 1e-3f;
        if ((v0 - v1) < eps || (v1 - v2) < eps) {
            const float* xr  = x + (size_t)g * D;
            const float* w0r = W + (size_t)i0 * D;
            const float* w1r = W + (size_t)i1 * D;
            const float* w2r = W + (size_t)i2 * D;
            double s0 = 0.0, s1 = 0.0, s2 = 0.0;
            for (int d = lane; d < D; d += 64) {
                const double xv = (double)xr[d];
                s0 += xv * (double)w0r[d];
                s1 += xv * (double)w1r[d];
                s2 += xv * (double)w2r[d];
            }
#pragma unroll
            for (int off = 32; off; off >>= 1) {
                s0 += __shfl_xor(s0, off);
                s1 += __shfl_xor(s1, off);
                s2 += __shfl_xor(s2, off);
            }
            double d0 = s0 + (double)noise[(size_t)g * EXPN + i0] * (double)nw[i0];
            double d1 = s1 + (double)noise[(size_t)g * EXPN + i1] * (double)nw[i1];
            double d2 = s2 + (double)noise[(size_t)g * EXPN + i2] * (double)nw[i2];
            // sort 3 (value desc, index asc on ties)
            #define CSWAP(va, ia, vb, ib)                                   \
                if ((vb > va) || (vb == va && ib < ia)) {                   \
                    double tv = va; va = vb; vb = tv;                       \
                    int ti = ia; ia = ib; ib = ti; }
            CSWAP(d0, i0, d1, i1)
            CSWAP(d1, i1, d2, i2)
            CSWAP(d0, i0, d1, i1)
            #undef CSWAP
            v0 = (float)d0; v1 = (float)d1;
        }

        const float e1  = expf(v1 - v0);
        const float inv = 1.0f / (1.0f + e1);

        float p = 0.f;
        if (lane == i0)      p = inv;
        else if (lane == i1) p = e1 * inv;
        probs[(size_t)g * EXPN + lane] = p;

        if (lane == 0) {
            idx_out[(size_t)g * 2 + 0] = (float)i0;
            idx_out[(size_t)g * 2 + 1] = (float)i1;
            val_out[(size_t)g * 2 + 0] = v0;
            val_out[(size_t)g * 2 + 1] = v1;
        }
    }
}

extern "C" void kernel_launch(void* const* d_in, const int* in_sizes, int n_in,
                              void* d_out, int out_size, void* d_ws, size_t ws_size,
                              hipStream_t stream) {
    const float* x     = (const float*)d_in[0];  // [B,S,D]
    const float* W     = (const float*)d_in[1];  // [E,D]
    const float* nw    = (const float*)d_in[2];  // [E]
    const float* noise = (const float*)d_in[3];  // [B,S,E]

    const int M = in_sizes[3] / EXPN;            // 16384 tokens
    const int D = in_sizes[0] / M;               // 2048
    const int wn = in_sizes[1];                  // E*D = 131072

    unsigned short* whp = (unsigned short*)d_ws;            // [E,D] bf16 hi
    unsigned short* wlp = whp + (size_t)wn;                 // [E,D] bf16 lo

    float* probs   = (float*)d_out;              // [M, E]
    float* idx_out = probs + (size_t)M * EXPN;   // [M, 2]
    float* val_out = idx_out + (size_t)M * 2;    // [M, 2]

    const int n4 = wn / 4;
    convert_w_kernel<<<(n4 + 255) / 256, 256, 0, stream>>>(W, whp, wlp, n4);

    const int grid = M / BM;                     // 512 blocks
    moe_gate_kernel<<<grid, 256, 0, stream>>>(x, W, whp, wlp, nw, noise,
                                              probs, idx_out, val_out, D);
}